// Round 8
// baseline (292.217 us; speedup 1.0000x reference)
//
#include <hip/hip_runtime.h>
#include <hip/hip_bf16.h>
#include <cstdint>
#include <cstddef>

// Problem constants
constexpr int Bb = 4;
constexpr int Tt = 2048;
constexpr int Mm = 1024;
constexpr int Hh = 2048;
constexpr int Ee = 8;
constexpr int Ss = Bb * Tt;   // 8192
constexpr int Cc = 2048;      // capacity per expert

typedef __attribute__((ext_vector_type(4))) float f32x4;
typedef __attribute__((ext_vector_type(8))) short bf16x8;

__device__ inline void load_lds16(const void* g, void* l) {
    __builtin_amdgcn_global_load_lds(
        (const __attribute__((address_space(1))) unsigned int*)g,
        (__attribute__((address_space(3))) unsigned int*)l, 16, 0, 0);
}

__device__ inline unsigned int pkbf(float lo, float hi) {
    __hip_bfloat16 l = __float2bfloat16(lo), h = __float2bfloat16(hi);
    unsigned short ls, hs;
    __builtin_memcpy(&ls, &l, 2); __builtin_memcpy(&hs, &h, 2);
    return (unsigned int)ls | ((unsigned int)hs << 16);
}

// ---------------- fused prep: w1 transpose+cast | w2sum/b2sum | gate + x->bf16 ----------------
// blocks [0,4096): w1 (E,M,H) fp32 -> w1t (E,H,M) bf16  [round-8: bf16-pair LDS transpose]
// blocks [4096,8192): w2sum[e,h] = sum_m w2[e,h,m]   block 8192: b2sum
// blocks [8193,10241): gating (one wave per token) + xbf emit
__global__ __launch_bounds__(256) void k_prep(
    const float* __restrict__ w1, const float* __restrict__ w2, const float* __restrict__ b2,
    const float* __restrict__ x, const float* __restrict__ wg,
    __hip_bfloat16* __restrict__ w1t, float* __restrict__ w2sum, float* __restrict__ b2sum,
    int* __restrict__ esel, float* __restrict__ gates, __hip_bfloat16* __restrict__ xbf) {
    int bid = blockIdx.x;
    int t = threadIdx.x;
    if (bid < 4096) {
        // 64(m) x 64(h) tile. LDS word w = h*33 + mw holds bf16 pair (m=2mw, 2mw+1) at h.
        // Write banks (4hq+j+mp)%32 -> worst 2-way (free). Read: 4 consecutive words =
        // final 8xbf16 output chunk, no repack; ~2-way max.
        __shared__ unsigned int tw[64 * 33];   // 8448 B
        int e = bid >> 9, m0 = ((bid >> 5) & 15) * 64, h0 = (bid & 31) * 64;
        const float* src = w1 + (size_t)e * Mm * Hh;
        #pragma unroll
        for (int i = 0; i < 2; i++) {
            int task = t + i * 256;          // [0,512)
            int mp = task >> 4;              // m-pair   [0,32)
            int hq = task & 15;              // h-quad   [0,16)
            const float* pa = src + (size_t)(m0 + 2 * mp) * Hh + h0 + hq * 4;
            float4 a = *(const float4*)pa;        // m even
            float4 b = *(const float4*)(pa + Hh); // m odd
            tw[(hq * 4 + 0) * 33 + mp] = pkbf(a.x, b.x);
            tw[(hq * 4 + 1) * 33 + mp] = pkbf(a.y, b.y);
            tw[(hq * 4 + 2) * 33 + mp] = pkbf(a.z, b.z);
            tw[(hq * 4 + 3) * 33 + mp] = pkbf(a.w, b.w);
        }
        __syncthreads();
        __hip_bfloat16* dst = w1t + (size_t)e * Hh * Mm;
        #pragma unroll
        for (int i = 0; i < 2; i++) {
            int task = t + i * 256;      // [0,512)
            int h = task >> 3;           // [0,64)
            int c8 = task & 7;           // m-chunk of 8 [0,8)
            const unsigned int* rowp = &tw[h * 33 + c8 * 4];
            uint4 v;
            v.x = rowp[0]; v.y = rowp[1]; v.z = rowp[2]; v.w = rowp[3];
            *(uint4*)(dst + (size_t)(h0 + h) * Mm + m0 + c8 * 8) = v;
        }
    } else if (bid < 8192) {
        // ---- w2sum: 4 rows per block (one per wave)
        int wave = t >> 6, lane = t & 63;
        int r = (bid - 4096) * 4 + wave;   // r in [0, E*H)
        const float4* p = (const float4*)(w2 + (size_t)r * Mm);
        float s = 0.f;
        #pragma unroll
        for (int i = 0; i < 4; i++) { float4 v = p[lane + i * 64]; s += v.x + v.y + v.z + v.w; }
        #pragma unroll
        for (int off = 32; off; off >>= 1) s += __shfl_down(s, off);
        if (lane == 0) w2sum[r] = s;
    } else if (bid == 8192) {
        // ---- b2sum: 4 waves x 2 half-waves = 8 experts
        int wave = t >> 6, lane = t & 63;
        int e = wave * 2 + (lane >> 5);
        int l = lane & 31;
        const float4* p = (const float4*)(b2 + (size_t)e * Mm);
        float s = 0.f;
        #pragma unroll
        for (int i = 0; i < 8; i++) { float4 v = p[l + i * 32]; s += v.x + v.y + v.z + v.w; }
        #pragma unroll
        for (int off = 16; off; off >>= 1) s += __shfl_down(s, off);
        if (l == 0) b2sum[e] = s;
    } else {
        // ---- gating: one wave per token + bf16 emit
        int gb = bid - 8193;
        int s = (gb * 256 + t) >> 6;   // token id
        int lane = t & 63;
        const float4* xr = (const float4*)(x + (size_t)s * Mm);
        const float4* wgr = (const float4*)wg;
        float acc[8];
        #pragma unroll
        for (int e = 0; e < 8; e++) acc[e] = 0.f;
        #pragma unroll
        for (int i = 0; i < 4; i++) {
            float4 xv = xr[lane + i * 64];
            uint2 u;
            u.x = pkbf(xv.x, xv.y);
            u.y = pkbf(xv.z, xv.w);
            *(uint2*)(xbf + (size_t)s * Mm + (lane + i * 64) * 4) = u;
            int mbase = (lane + i * 64) * 4;
            #pragma unroll
            for (int k = 0; k < 4; k++) {
                int m = mbase + k;
                float xm = (k == 0) ? xv.x : (k == 1) ? xv.y : (k == 2) ? xv.z : xv.w;
                float4 w0 = wgr[m * 2], w1v = wgr[m * 2 + 1];
                acc[0] += xm * w0.x;  acc[1] += xm * w0.y;  acc[2] += xm * w0.z;  acc[3] += xm * w0.w;
                acc[4] += xm * w1v.x; acc[5] += xm * w1v.y; acc[6] += xm * w1v.z; acc[7] += xm * w1v.w;
            }
        }
        #pragma unroll
        for (int off = 32; off; off >>= 1)
            #pragma unroll
            for (int e = 0; e < 8; e++) acc[e] += __shfl_down(acc[e], off);
        if (lane == 0) {
            float mx = acc[0];
            #pragma unroll
            for (int e = 1; e < 8; e++) mx = fmaxf(mx, acc[e]);
            float p[8], se = 0.f;
            #pragma unroll
            for (int e = 0; e < 8; e++) { p[e] = expf(acc[e] - mx); se += p[e]; }
            float inv = 1.f / se;
            #pragma unroll
            for (int e = 0; e < 8; e++) p[e] *= inv;
            int i0 = 0; float v0 = p[0];
            #pragma unroll
            for (int e = 1; e < 8; e++) if (p[e] > v0) { v0 = p[e]; i0 = e; }
            int i1 = -1; float v1 = -1.f;
            #pragma unroll
            for (int e = 0; e < 8; e++) if (e != i0 && p[e] > v1) { v1 = p[e]; i1 = e; }
            float den = v0 + v1 + 1e-9f;
            esel[s] = i0; esel[Ss + s] = i1;
            gates[s] = v0 / den; gates[Ss + s] = v1 / den;
        }
    }
}

// ---------------- positions: parallel 2-phase scan ----------------
__global__ __launch_bounds__(256) void k_posA(const int* __restrict__ esel,
                                              int* __restrict__ lrank, int* __restrict__ blockhist) {
    int b = blockIdx.x, t = threadIdx.x;
    int d = b * 256 + t;
    int e = esel[d];
    int wave = t >> 6, lane = t & 63;
    __shared__ int wh[4][8];
    unsigned long long mymask = 0;
    #pragma unroll
    for (int q = 0; q < 8; q++) {
        unsigned long long m = __ballot(e == q);
        if (q == e) mymask = m;
        if (lane == 0) wh[wave][q] = (int)__popcll(m);
    }
    __syncthreads();
    int prefix = (int)__popcll(mymask & ((1ull << lane) - 1ull));
    for (int w = 0; w < wave; w++) prefix += wh[w][e];
    lrank[d] = prefix;
    if (t < 8) blockhist[b * 8 + t] = wh[0][t] + wh[1][t] + wh[2][t] + wh[3][t];
}

// ---------------- finalize positions + inverse index (scan folded in; k_posB removed) ----------------
__global__ __launch_bounds__(256) void k_sidx(const int* __restrict__ esel,
                                              const int* __restrict__ lrank,
                                              const int* __restrict__ blockhist,
                                              int* __restrict__ pos, int* __restrict__ srcidx) {
    __shared__ int base_s[8];
    int bid = blockIdx.x, t = threadIdx.x;
    if (t < 64) {
        // wave 0: lane l contributes blockhist[l][e] for l < bid; shuffle-reduce per expert
        #pragma unroll
        for (int e8 = 0; e8 < 8; e8++) {
            int v = (t < bid) ? blockhist[t * 8 + e8] : 0;
            #pragma unroll
            for (int off = 32; off; off >>= 1) v += __shfl_down(v, off);
            if (t == 0) base_s[e8] = v;
        }
    }
    __syncthreads();
    int d = bid * 256 + t;
    int e = esel[d];
    int p = base_s[e] + lrank[d];
    pos[d] = p;
    if (p < Cc) srcidx[e * Cc + p] = d & (Ss - 1);
}

// ---------------- fused expert GEMM: 256x256 tile, 8-phase schedule (unchanged from r7) ----------------
__global__ __launch_bounds__(512, 2) void k_gemm(
    const __hip_bfloat16* __restrict__ xbf, const int* __restrict__ srcidx,
    const __hip_bfloat16* __restrict__ w1t,
    const float* __restrict__ b1, const float* __restrict__ w2sum,
    float* __restrict__ rowsum) {
    __shared__ __align__(16) __hip_bfloat16 A_lds[2][2][8192];   // [db][khalf][256r x 32k]
    __shared__ __align__(16) __hip_bfloat16 B_lds[2][2][8192];
    int bid = blockIdx.x;
    int e = bid & 7;                  // XCD-affine: expert e -> XCD e
    int tile = bid >> 3;              // [0,64)
    int cb = tile >> 3, hb = tile & 7;
    int c0 = cb * 256, h0 = hb * 256;
    int t = threadIdx.x;              // [0,512)
    int wave = t >> 6, lane = t & 63;
    int wm = wave >> 2;               // c-half   [0,2)
    int wn = wave & 3;                // h-quarter [0,4)
    int r16 = lane & 15, quad = lane >> 4;
    int r_s = t >> 2;
    int qd = ((t & 3) - ((t >> 3) & 3)) & 3;
    int s0 = srcidx[e * Cc + c0 + r_s];
    int s1 = srcidx[e * Cc + c0 + 128 + r_s];
    const __hip_bfloat16* a0 = xbf + (size_t)s0 * Mm + qd * 8;
    const __hip_bfloat16* a1 = xbf + (size_t)s1 * Mm + qd * 8;
    const __hip_bfloat16* Bp = w1t + (size_t)e * Hh * Mm;
    const __hip_bfloat16* b0 = Bp + (size_t)(h0 + r_s) * Mm + qd * 8;
    const __hip_bfloat16* b1p = Bp + (size_t)(h0 + 128 + r_s) * Mm + qd * 8;
    int fo = r16 * 4 + ((quad + (r16 >> 1)) & 3);
    int lsl = t * 8, hsl = (512 + t) * 8;
    f32x4 acc[8][4];
    #pragma unroll
    for (int i = 0; i < 8; i++)
        #pragma unroll
        for (int j = 0; j < 4; j++) acc[i][j] = (f32x4){0.f, 0.f, 0.f, 0.f};

#define STAGE_A(DB, KK, T) do { \
    load_lds16(a0 + (T) * 64 + (KK) * 32, &A_lds[DB][KK][lsl]); \
    load_lds16(a1 + (T) * 64 + (KK) * 32, &A_lds[DB][KK][hsl]); } while (0);
#define STAGE_B(DB, KK, T) do { \
    load_lds16(b0 + (T) * 64 + (KK) * 32, &B_lds[DB][KK][lsl]); \
    load_lds16(b1p + (T) * 64 + (KK) * 32, &B_lds[DB][KK][hsl]); } while (0);
#define NOSTAGE
#define VM8 asm volatile("s_waitcnt vmcnt(8)" ::: "memory");
#define VM4 asm volatile("s_waitcnt vmcnt(4)" ::: "memory");
#define VM0 asm volatile("s_waitcnt vmcnt(0)" ::: "memory");
#define VMNONE

#define PHASE(DB, KK, MH, STAGE_STMT, VM_STMT) do { \
    __builtin_amdgcn_sched_barrier(0); \
    bf16x8 paf[4], pbf[4]; \
    const __hip_bfloat16* Ab_ = &A_lds[DB][KK][0]; \
    const __hip_bfloat16* Bb_ = &B_lds[DB][KK][0]; \
    _Pragma("unroll") \
    for (int q_ = 0; q_ < 4; q_++) { \
        paf[q_] = *(const bf16x8*)(Ab_ + ((wm * 8 + (MH) * 4 + q_) * 64 + fo) * 8); \
        pbf[q_] = *(const bf16x8*)(Bb_ + ((wn * 4 + q_) * 64 + fo) * 8); \
    } \
    STAGE_STMT \
    __builtin_amdgcn_s_barrier(); \
    asm volatile("s_waitcnt lgkmcnt(0)" ::: "memory"); \
    __builtin_amdgcn_sched_barrier(0); \
    __builtin_amdgcn_s_setprio(1); \
    _Pragma("unroll") \
    for (int mi_ = 0; mi_ < 4; mi_++) \
        _Pragma("unroll") \
        for (int ni_ = 0; ni_ < 4; ni_++) \
            acc[(MH) * 4 + mi_][ni_] = __builtin_amdgcn_mfma_f32_16x16x32_bf16( \
                paf[mi_], pbf[ni_], acc[(MH) * 4 + mi_][ni_], 0, 0, 0); \
    __builtin_amdgcn_s_setprio(0); \
    __builtin_amdgcn_sched_barrier(0); \
    VM_STMT \
    __builtin_amdgcn_s_barrier(); \
} while (0)

    // prologue: quarters needed through iter-0 P6
    STAGE_A(0, 0, 0) STAGE_B(0, 0, 0) STAGE_A(0, 1, 0) STAGE_B(0, 1, 0)
    STAGE_A(1, 0, 1) STAGE_B(1, 0, 1)
    asm volatile("s_waitcnt vmcnt(8)" ::: "memory");
    __builtin_amdgcn_s_barrier();

    for (int i = 0; i < 7; ++i) {
        int T1 = 2 * i + 1, T2 = 2 * i + 2, T3 = 2 * i + 3;
        PHASE(0, 0, 0, STAGE_A(1, 1, T1), VMNONE);
        PHASE(0, 0, 1, STAGE_B(1, 1, T1), VM8);
        PHASE(0, 1, 0, STAGE_A(0, 0, T2), VMNONE);
        PHASE(0, 1, 1, STAGE_B(0, 0, T2), VM8);
        PHASE(1, 0, 0, STAGE_A(0, 1, T2), VMNONE);
        PHASE(1, 0, 1, STAGE_B(0, 1, T2), VM8);
        PHASE(1, 1, 0, STAGE_A(1, 0, T3), VMNONE);
        PHASE(1, 1, 1, STAGE_B(1, 0, T3), VM8);
    }
    // peeled last iteration (tiles 14, 15)
    PHASE(0, 0, 0, STAGE_A(1, 1, 15), VMNONE);
    PHASE(0, 0, 1, STAGE_B(1, 1, 15), VM8);
    PHASE(0, 1, 0, NOSTAGE, VMNONE);
    PHASE(0, 1, 1, NOSTAGE, VM4);
    PHASE(1, 0, 0, NOSTAGE, VMNONE);
    PHASE(1, 0, 1, NOSTAGE, VM0);
    PHASE(1, 1, 0, NOSTAGE, VMNONE);
    PHASE(1, 1, 1, NOSTAGE, VMNONE);

    // epilogue: relu(s + b1) * w2sum, reduce over h, atomic into rowsum[e, c]
    float b1v[4], wsv[4];
    #pragma unroll
    for (int ni = 0; ni < 4; ni++) {
        int hg = h0 + wn * 64 + ni * 16 + r16;
        b1v[ni] = b1[e * Hh + hg];
        wsv[ni] = w2sum[e * Hh + hg];
    }
    #pragma unroll
    for (int mi = 0; mi < 8; mi++) {
        #pragma unroll
        for (int r = 0; r < 4; r++) {
            float val = 0.f;
            #pragma unroll
            for (int ni = 0; ni < 4; ni++) {
                float sv = acc[mi][ni][r] + b1v[ni];
                val += fmaxf(sv, 0.f) * wsv[ni];
            }
            #pragma unroll
            for (int off = 1; off < 16; off <<= 1) val += __shfl_xor(val, off);
            if (r16 == 0) {
                int cg = c0 + wm * 128 + mi * 16 + quad * 4 + r;
                atomicAdd(&rowsum[e * Cc + cg], val);
            }
        }
    }
}

// ---------------- combine + per-batch log-softmax (k_combine folded in) ----------------
__global__ __launch_bounds__(1024) void k_lsm(
    const int* __restrict__ esel, const int* __restrict__ pos,
    const float* __restrict__ gates, const float* __restrict__ rowsum,
    const float* __restrict__ b2sum, float* __restrict__ out) {
    int b = blockIdx.x; int t = threadIdx.x;
    __shared__ float red[1024];
    float vv[2];
    #pragma unroll
    for (int i = 0; i < 2; i++) {
        int s = b * Tt + t + i * 1024;
        float acc = 0.f;
        #pragma unroll
        for (int j = 0; j < 2; j++) {
            int d = j * Ss + s;
            int p = pos[d];
            if (p < Cc) {
                int ee = esel[d];
                acc += gates[d] * (rowsum[ee * Cc + p] + b2sum[ee]);
            }
        }
        vv[i] = acc;
    }
    float m = fmaxf(vv[0], vv[1]);
    red[t] = m; __syncthreads();
    for (int st = 512; st; st >>= 1) { if (t < st) red[t] = fmaxf(red[t], red[t + st]); __syncthreads(); }
    float mx = red[0];
    __syncthreads();
    float se = expf(vv[0] - mx) + expf(vv[1] - mx);
    red[t] = se; __syncthreads();
    for (int st = 512; st; st >>= 1) { if (t < st) red[t] += red[t + st]; __syncthreads(); }
    float lse = logf(red[0]);
    out[b * Tt + t] = vv[0] - mx - lse;
    out[b * Tt + t + 1024] = vv[1] - mx - lse;
}

extern "C" void kernel_launch(void* const* d_in, const int* in_sizes, int n_in,
                              void* d_out, int out_size, void* d_ws, size_t ws_size,
                              hipStream_t stream) {
    const float* x  = (const float*)d_in[0];
    const float* wg = (const float*)d_in[1];
    const float* w1 = (const float*)d_in[2];
    const float* b1 = (const float*)d_in[3];
    const float* w2 = (const float*)d_in[4];
    const float* b2 = (const float*)d_in[5];
    float* out = (float*)d_out;

    char* ws = (char*)d_ws;
    size_t off = 0;
    auto alloc = [&](size_t bytes) -> void* {
        void* p = ws + off;
        off += (bytes + 255) & ~(size_t)255;
        return p;
    };
    // rowsum + srcidx adjacent -> single memset
    float* rowsum   = (float*)alloc((size_t)Ee * Cc * 4 + (size_t)Ee * Cc * 4);
    int*   srcidx   = (int*)(rowsum + (size_t)Ee * Cc);
    float* w2sum    = (float*)alloc((size_t)Ee * Hh * 4);
    float* b2sum    = (float*)alloc(Ee * 4);
    int*   esel     = (int*)alloc((size_t)2 * Ss * 4);
    int*   lrank    = (int*)alloc((size_t)2 * Ss * 4);
    int*   blockhist= (int*)alloc((size_t)64 * 8 * 4);
    int*   pos      = (int*)alloc((size_t)2 * Ss * 4);
    float* gates    = (float*)alloc((size_t)2 * Ss * 4);
    __hip_bfloat16* xbf = (__hip_bfloat16*)alloc((size_t)Ss * Mm * 2);
    __hip_bfloat16* w1t = (__hip_bfloat16*)alloc((size_t)Ee * Hh * Mm * 2);

    hipMemsetAsync(rowsum, 0, (size_t)2 * Ee * Cc * 4, stream);
    k_prep<<<10241, 256, 0, stream>>>(w1, w2, b2, x, wg, w1t, w2sum, b2sum, esel, gates, xbf);
    k_posA<<<64, 256, 0, stream>>>(esel, lrank, blockhist);
    k_sidx<<<64, 256, 0, stream>>>(esel, lrank, blockhist, pos, srcidx);
    k_gemm<<<512, 512, 0, stream>>>(xbf, srcidx, w1t, b1, w2sum, rowsum);
    k_lsm<<<Bb, 1024, 0, stream>>>(esel, pos, gates, rowsum, b2sum, out);
}